// Round 16
// baseline (334.273 us; speedup 1.0000x reference)
//
#include <hip/hip_runtime.h>
#include <math.h>

#define NB   256
#define ND   63
#define NN   3969        // 63*63
#define WST  1028        // wbuf tap stride (1028%32=4 -> bank spread across taps)

__device__ __forceinline__ float gelu_f(float v){
    return 0.5f * v * (1.0f + erff(v * 0.70710678118654752440f));
}

#define FMA4(A, W, S) { (A).x=fmaf((W).x,(S),(A).x); (A).y=fmaf((W).y,(S),(A).y); \
                        (A).z=fmaf((W).z,(S),(A).z); (A).w=fmaf((W).w,(S),(A).w); }

union F4  { float4 v;    float a[4];  };
union W16 { float4 v[4]; float a[16]; };

__device__ __forceinline__ float4 gelu4(const F4& x){
    float4 r;
    r.x = gelu_f(x.a[0]); r.y = gelu_f(x.a[1]);
    r.z = gelu_f(x.a[2]); r.w = gelu_f(x.a[3]);
    return r;
}

// pair-base decode: units 0..H-1 are x-pairs (ox,ox+2), unit H is the singleton 2H.
__device__ __forceinline__ int dec_base(int uc, int H){
    int h2 = H >> 1;
    return (uc < h2) ? 4*uc : (uc < H) ? 4*(uc - h2) + 1 : 2*H;
}

// ---- 2x2-quad ConvTranspose stage (NT = block size, [u0,u1) unit range) ----
template<int SIN, int SOUT, int OST, int NT>
__device__ __forceinline__ void ct_quad_stage(const float* __restrict__ cin,
                                              float* __restrict__ cout,
                                              const float* __restrict__ wb,
                                              const float* __restrict__ bsv,
                                              int tid, int u0, int u1){
    const int H  = (SOUT - 1) >> 1;
    const int UX = H + 1;
    const int NU = UX * UX * 8;
    if (u1 > NU) u1 = NU;
    for (int u = u0 + tid; u < u1; u += NT){
        const int cell = u >> 3, q = u & 7;
        const int ucy = cell / UX, ucx = cell - ucy*UX;
        const int oy = dec_base(ucy, H), ox = dec_base(ucx, H);
        const bool vx = (ox + 2 <= 2*H), vy = (oy + 2 <= 2*H);
        int nky, kyA[2], iyA[2];
        if (oy & 1){ nky=2; kyA[0]=0; iyA[0]=(oy+1)>>1; kyA[1]=2; iyA[1]=(oy-1)>>1; }
        else       { nky=1; kyA[0]=1; iyA[0]=oy>>1; kyA[1]=1; iyA[1]=0; }
        int nkx, kxA[2], ixA[2];
        if (ox & 1){ nkx=2; kxA[0]=0; ixA[0]=(ox+1)>>1; kxA[1]=2; ixA[1]=(ox-1)>>1; }
        else       { nkx=1; kxA[0]=1; ixA[0]=ox>>1; kxA[1]=1; ixA[1]=0; }
        F4 a00, a01, a10, a11;
        a00.v = ((const float4*)bsv)[q]; a01.v = a00.v; a10.v = a00.v; a11.v = a00.v;
        for (int yi = 0; yi < nky; yi++)
        for (int xi = 0; xi < nkx; xi++){
            const float* wp  = wb + (kyA[yi]*3 + kxA[xi])*WST + 4*q;
            const float* p00 = cin + (iyA[yi]*SIN + ixA[xi])*36;
            const float* p01 = p00 + 36;
            const float* p10 = p00 + SIN*36;
            const float* p11 = p10 + 36;
            #pragma unroll
            for (int g = 0; g < 8; g++){
                F4 i00, i01, i10, i11;
                i00.v = *(const float4*)(p00 + 4*g);
                i01.v = *(const float4*)(p01 + 4*g);
                i10.v = *(const float4*)(p10 + 4*g);
                i11.v = *(const float4*)(p11 + 4*g);
                #pragma unroll
                for (int cc = 0; cc < 4; cc++){
                    float4 w = *(const float4*)(wp + (4*g + cc)*32);
                    FMA4(a00.v, w, i00.a[cc]);
                    FMA4(a01.v, w, i01.a[cc]);
                    FMA4(a10.v, w, i10.a[cc]);
                    FMA4(a11.v, w, i11.a[cc]);
                }
            }
        }
        float4 g00 = gelu4(a00), g01 = gelu4(a01), g10 = gelu4(a10), g11 = gelu4(a11);
        size_t base = (size_t)(oy*SOUT + ox)*OST + 4*q;
        *(float4*)(cout + base) = g00;
        if (vx)        *(float4*)(cout + base + 2*(size_t)OST) = g01;
        if (vy)        *(float4*)(cout + base + 2*(size_t)SOUT*OST) = g10;
        if (vx && vy)  *(float4*)(cout + base + 2*(size_t)(SOUT+1)*OST) = g11;
    }
}

// ---- ct1..ct3 per sample (1024 thr); writes c3 (17x17x32 channel-last) to global ----
__global__ __launch_bounds__(1024)
__attribute__((amdgpu_waves_per_eu(4, 4)))
void k_ct123(const float* __restrict__ kA,
             const float* __restrict__ cw1,
             const float* __restrict__ cw2,
             const float* __restrict__ cw3,
             const float* __restrict__ b1,
             const float* __restrict__ b2,
             const float* __restrict__ b3,
             float* __restrict__ c3out,
             float* __restrict__ acc){
    __shared__ __align__(16) float wbuf[9*WST];  // [tap(1028)][ci][co32]
    __shared__ __align__(16) float w1s[9*36];    // [tap(36)][co32]
    __shared__ __align__(16) float c1s[31*36];   // [px][ci] stride 36
    __shared__ __align__(16) float c2s[91*36];
    __shared__ __align__(16) float c3s[307*36];
    __shared__ float b1s[32], b2s[32], b3s[32];
    const int b = blockIdx.x, tid = threadIdx.x;
    if (b == 0 && tid == 0) acc[0] = 0.f;
    for (int i = tid; i < 9216; i += 1024){
        int ci = i / 288, co = (i / 9) & 31, tap = i % 9;
        wbuf[tap*WST + ci*32 + co] = cw2[i];
    }
    if (tid < 288) w1s[(tid % 9)*36 + tid/9] = cw1[tid];
    if (tid < 32){ b1s[tid]=b1[tid]; b2s[tid]=b2[tid]; b3s[tid]=b3[tid]; }
    __syncthreads();
    // ---- ct1: 3x3 -> 5x5, 1->32. 200 units ----
    if (tid < 200){
        int px = tid >> 3, q = tid & 7;
        int oy = px / 5, ox = px % 5;
        F4 a4; a4.v = ((const float4*)b1s)[q];
        int nky, kyA[2], iyA[2];
        if (oy & 1){ nky=2; kyA[0]=0; iyA[0]=(oy+1)/2; kyA[1]=2; iyA[1]=(oy-1)/2; }
        else       { nky=1; kyA[0]=1; iyA[0]=oy/2; kyA[1]=1; iyA[1]=0; }
        int nkx, kxA[2], ixA[2];
        if (ox & 1){ nkx=2; kxA[0]=0; ixA[0]=(ox+1)/2; kxA[1]=2; ixA[1]=(ox-1)/2; }
        else       { nkx=1; kxA[0]=1; ixA[0]=ox/2; kxA[1]=1; ixA[1]=0; }
        const float* ab = kA + b*9;
        for (int yi = 0; yi < nky; yi++)
        for (int xi = 0; xi < nkx; xi++){
            float v = ab[iyA[yi]*3 + ixA[xi]];
            float4 w = *(const float4*)(w1s + (kyA[yi]*3 + kxA[xi])*36 + 4*q);
            FMA4(a4.v, w, v);
        }
        *(float4*)(c1s + px*36 + 4*q) = gelu4(a4);
    }
    __syncthreads();
    ct_quad_stage<5, 9, 36, 1024>(c1s, c2s, wbuf, b2s, tid, 0, 1<<30);   // ct2: 5->9
    __syncthreads();
    for (int i = tid; i < 9216; i += 1024){
        int ci = i / 288, co = (i / 9) & 31, tap = i % 9;
        wbuf[tap*WST + ci*32 + co] = cw3[i];
    }
    __syncthreads();
    ct_quad_stage<9, 17, 36, 1024>(c2s, c3s, wbuf, b3s, tid, 0, 1<<30);  // ct3: 9->17
    __syncthreads();
    // write c3 channel-last [289][32] to global
    float* cg = c3out + (size_t)b * 9248;
    for (int i = tid; i < 9248; i += 1024) cg[i] = c3s[(i >> 5)*36 + (i & 31)];
}

// ---- ct4 per sample, SPLIT over 2 blocks (grid 512 -> 2 blocks/CU, 32 waves) ----
// LDS = 9252 + 11052 + 32 floats = 81,344 B < 81,920 (2-block budget).
__global__ __launch_bounds__(512) void k_ct4(const float* __restrict__ c3g,
                                             const float* __restrict__ cw4,
                                             const float* __restrict__ b4,
                                             float* __restrict__ c4out){
    __shared__ __align__(16) float wbuf[9*WST];
    __shared__ __align__(16) float c3s[307*36];
    __shared__ float b4s[32];
    const int sample = blockIdx.x >> 1, half = blockIdx.x & 1, tid = threadIdx.x;
    for (int i = tid; i < 9216; i += 512){
        int ci = i / 288, co = (i / 9) & 31, tap = i % 9;
        wbuf[tap*WST + ci*32 + co] = cw4[i];
    }
    const float* cg = c3g + (size_t)sample * 9248;
    for (int i = tid; i < 9248; i += 512) c3s[(i >> 5)*36 + (i & 31)] = cg[i];
    // zero pad rows 289..306 (read by masked lanes; must be finite)
    for (int i = tid; i < 307*36 - 289*36; i += 512) c3s[289*36 + i] = 0.f;
    if (tid < 32) b4s[tid] = b4[tid];
    __syncthreads();
    // ct4: 17->33, channel-last to global; units [half*1156, half*1156+1156) of 2312
    ct_quad_stage<17, 33, 32, 512>(c3s, c4out + (size_t)sample*(1089*32), wbuf, b4s,
                                   tid, half*1156, half*1156 + 1156);
}

// ---------------- mega solver, 512 threads, Hermitian-halved DFT -------------
// r14 state (328.1us, absmax 0.0). UNCHANGED this round.
__global__ __launch_bounds__(512) void k_solve(const float* __restrict__ x0g,
                                               const float* __restrict__ f,
                                               const float* __restrict__ kAg,
                                               const float* __restrict__ w1a, const float* __restrict__ b1a,
                                               const float* __restrict__ w2a, const float* __restrict__ b2a,
                                               const float* __restrict__ w1b, const float* __restrict__ b1b,
                                               const float* __restrict__ w2b, const float* __restrict__ b2b,
                                               const float* __restrict__ cw5,
                                               const float* __restrict__ b5,
                                               const float* __restrict__ c4g,
                                               float* __restrict__ accg){
    __shared__ __align__(16) float xs[65*68 + 8];    // padded: 65 rows x stride 68
    __shared__ __align__(16) float U[17152 + 8];     // c5s / rs+tc0+tc1+tc2 / rP|TtC|MC|CC
    __shared__ __align__(16) float Fs_r[32*68 + 8];  // F real, rows 0..31, stride 68
    __shared__ __align__(16) float Fs_i[32*68 + 8];  // F imag
    __shared__ __align__(16) float vcs[4096];        // v rows 0..31 interleaved (f4)
    __shared__ float ws5b[9*68];
    __shared__ float w1s[148], w2s[148], dvs[64], ds_r[32], ds_i[32], red[8], hs[100];
    const int b = blockIdx.x, tid = threadIdx.x;
    float* rs  = U;
    float* tc0 = U + 4288;
    float* tc1 = U + 8576;
    float* tc2 = U + 12864;
    float*  rP  = U;                                 // 63 rows x stride 68
    const float4* rP4 = (const float4*)U;            // row stride 17 f4
    float2* TtC = (float2*)(U + 4352);               // 4352..8447
    float2* MC2 = (float2*)(U + 8448);               // 8448..12543 (disjoint from rP/TtC)
    float4* CC4 = (float4*)(U + 12544);              // 12544..16767
    float* c5s = U;
    const float4* F4r = (const float4*)Fs_r;
    const float4* F4i = (const float4*)Fs_i;
    const float4* vc4s = (const float4*)vcs;
    const float* fg = f + (size_t)b*NN;
    float ka[9];
    #pragma unroll
    for (int i = 0; i < 9; i++) ka[i] = kAg[b*9 + i];

    // ================= prologue =================
    for (int i = tid; i < 2176; i += 512){
        int r = i / 68, c = i % 68;
        float vr = 0.f, vi = 0.f;
        if (c < 63){
            int m = (r * c) % 63;
            float ang = 6.283185307179586f * (float)m / 63.0f;
            vr = cosf(ang); vi = -sinf(ang);
        }
        Fs_r[i] = vr; Fs_i[i] = vi;
    }
    // padded-xs boundary init (skip interior: rows 1..63 x cols 4..66)
    for (int i = tid; i < 4428; i += 512){
        int r = i / 68, c = i - r*68;
        bool interior = (r >= 1 && r <= 63 && c >= 4 && c <= 66);
        if (!interior) xs[i] = (r == 64 || c == 67) ? 1.f : 0.f;
    }
    for (int i = tid; i < 576; i += 512){
        int ci = i / 18, co = (i / 9) & 1, tap = i % 9;
        ws5b[tap*68 + ci*2 + co] = cw5[i];
    }
    for (int i = tid; i < NN; i += 512) xs[(i/ND + 1)*68 + (i%ND) + 4] = x0g[(size_t)b*NN + i];
    // hypernet MLP (both stacks), outputs straight into w1s/w2s
    if (tid < 100){
        float s = b1a[tid];
        #pragma unroll
        for (int i = 0; i < 9; i++) s = fmaf(ka[i], w1a[i*100 + tid], s);
        hs[tid] = gelu_f(s);
    }
    __syncthreads();
    if (tid < 147){
        float s = b2a[tid];
        for (int k = 0; k < 100; k++) s = fmaf(hs[k], w2a[k*147 + tid], s);
        w1s[tid] = s;
    }
    __syncthreads();
    if (tid < 100){
        float s = b1b[tid];
        #pragma unroll
        for (int i = 0; i < 9; i++) s = fmaf(ka[i], w1b[i*100 + tid], s);
        hs[tid] = gelu_f(s);
    }
    __syncthreads();
    if (tid < 147){
        float s = b2b[tid];
        for (int k = 0; k < 100; k++) s = fmaf(hs[k], w2b[k*147 + tid], s);
        w2s[tid] = s;
    }
    // ct5 from c4 -> c5s (in U)
    {
        const float* ib = c4g + (size_t)b * (1089*32);
        float bb0 = b5[0], bb1 = b5[1];
        for (int p = tid; p < NN; p += 512){
            int oy = p / ND, ox = p % ND;
            float a0 = bb0, a1 = bb1;
            int nky, kyA[2], iyA[2];
            if ((oy & 1) == 0){ nky=2; kyA[0]=0; iyA[0]=oy/2+1; kyA[1]=2; iyA[1]=oy/2; }
            else              { nky=1; kyA[0]=1; iyA[0]=(oy+1)/2; kyA[1]=1; iyA[1]=0; }
            int nkx, kxA[2], ixA[2];
            if ((ox & 1) == 0){ nkx=2; kxA[0]=0; ixA[0]=ox/2+1; kxA[1]=2; ixA[1]=ox/2; }
            else              { nkx=1; kxA[0]=1; ixA[0]=(ox+1)/2; kxA[1]=1; ixA[1]=0; }
            for (int yi = 0; yi < nky; yi++)
            for (int xi = 0; xi < nkx; xi++){
                const float* ip = ib + ((size_t)iyA[yi]*33 + ixA[xi])*32;
                const float* wp = ws5b + (kyA[yi]*3 + kxA[xi])*68;
                #pragma unroll
                for (int g = 0; g < 8; g++){
                    F4 iv; iv.v = *(const float4*)(ip + 4*g);
                    #pragma unroll
                    for (int q = 0; q < 4; q++){
                        int ci = 4*g + q;
                        a0 = fmaf(iv.a[q], wp[ci*2],   a0);
                        a1 = fmaf(iv.a[q], wp[ci*2+1], a1);
                    }
                }
            }
            c5s[p]      = a0;
            c5s[NN + p] = a1;
        }
    }
    __syncthreads();
    // build vcs (rows 0..31, interleaved re/im pairs) + dvs
    {
        const float sc = 1.0f / 3969.0f;
        float4* vout = (float4*)vcs;
        for (int i = tid; i < 1024; i += 512){
            int ky = i >> 5, ct2 = i & 31;
            float4 o;
            #pragma unroll
            for (int j = 0; j < 2; j++){
                int kx = 2*ct2 + j;
                float re = 0.f, im = 0.f;
                if (kx <= 31){ int o2 = 2*(ky*ND + kx); re = c5s[o2]*sc; im = c5s[o2+1]*sc; }
                else if (kx <= 62){
                    int sy = (ND - ky) % ND, sx = ND - kx;
                    int o2 = 2*(sy*ND + sx); re = c5s[o2]*sc; im = -c5s[o2+1]*sc;
                }
                if (j == 0){ o.x = re; o.y = im; } else { o.z = re; o.w = im; }
            }
            vout[i] = o;
        }
        if (tid < 32){
            float2 d = {0.f, 0.f};
            if (tid >= 1){
                int iA = (ND - tid) * ND, iB = tid * ND;
                d.x = (c5s[2*iA]     - c5s[2*iB])     * sc;
                d.y = (c5s[2*iA + 1] + c5s[2*iB + 1]) * sc;
            }
            ((float2*)dvs)[tid] = d;
        }
    }
    __syncthreads();

    const int kt = tid >> 4, cg = tid & 15;
    const bool act = tid < 504;
    const int y0 = tid >> 3, xc = 8*(tid & 7);

    for (int it = 0; it < 5; it++){
        // ---- residual -> rs: branchless stencil on padded xs ----
        if (act){
            float racc[8] = {};
            #pragma unroll
            for (int dy = 0; dy < 3; dy++){
                W16 w;
                const float4* rp = (const float4*)(xs + (y0 + dy)*68 + xc);
                w.v[0]=rp[0]; w.v[1]=rp[1]; w.v[2]=rp[2]; w.v[3]=rp[3];
                #pragma unroll
                for (int dx = 0; dx < 3; dx++){
                    float kv = ka[dy*3 + dx];
                    #pragma unroll
                    for (int t = 0; t < 8; t++) racc[t] = fmaf(kv, w.a[3 + t + dx], racc[t]);
                }
            }
            int nw = 63 - xc; if (nw > 8) nw = 8;
            const float* fr_ = fg + y0*ND + xc;
            for (int t = 0; t < nw; t++) rs[y0*68 + 3 + xc + t] = fr_[t] - racc[t];
        }
        // borders: cols {0,1,2,66,67} of 63 rows + 4-float tail, for each of
        // rs,tc0,tc1,tc2 (these bytes are scribbled by the DFT unions each iter)
        for (int i = tid; i < 1276; i += 512){
            int buf = i / 319, j = i - buf*319;
            float* base = U + buf*4288;
            int idx;
            if (j < 315){ int rr = j/5, cc = j - rr*5; idx = rr*68 + ((cc < 3) ? cc : 63 + cc); }
            else idx = 4284 + (j - 315);
            base[idx] = 0.f;
        }
        __syncthreads();
        // ---- smoother pass1: all 3 channels, shared row loads -> tc0/1/2 ----
        if (act){
            float A0[8] = {}, A1[8] = {}, A2[8] = {};
            for (int dy = 0; dy < 7; dy++){
                int ry = y0 + dy - 3;
                if (ry < 0 || ry >= 63) continue;
                W16 w16;
                const float4* rp = (const float4*)(rs + ry*68 + xc);
                w16.v[0]=rp[0]; w16.v[1]=rp[1]; w16.v[2]=rp[2]; w16.v[3]=rp[3];
                #pragma unroll
                for (int dx = 0; dx < 7; dx++){
                    float w0 = w1s[dy*7 + dx];
                    float w1 = w1s[49 + dy*7 + dx];
                    float w2 = w1s[98 + dy*7 + dx];
                    #pragma unroll
                    for (int t = 0; t < 8; t++){
                        float v = w16.a[t+dx];
                        A0[t] = fmaf(w0, v, A0[t]);
                        A1[t] = fmaf(w1, v, A1[t]);
                        A2[t] = fmaf(w2, v, A2[t]);
                    }
                }
            }
            int nw = 63 - xc; if (nw > 8) nw = 8;
            for (int t = 0; t < nw; t++){
                int o = y0*68 + 3 + xc + t;
                tc0[o] = A0[t]; tc1[o] = A1[t]; tc2[o] = A2[t];
            }
        }
        __syncthreads();
        // ---- smoother pass2: accumulate 3 channels, update x (padded layout) ----
        if (act){
            float acc2[8] = {};
            #pragma unroll
            for (int c = 0; c < 3; c++){
                const float* tcc = (c == 0) ? tc0 : (c == 1) ? tc1 : tc2;
                for (int dy = 0; dy < 7; dy++){
                    int ry = y0 + dy - 3;
                    if (ry < 0 || ry >= 63) continue;
                    W16 w16;
                    const float4* tp = (const float4*)(tcc + ry*68 + xc);
                    w16.v[0]=tp[0]; w16.v[1]=tp[1]; w16.v[2]=tp[2]; w16.v[3]=tp[3];
                    #pragma unroll
                    for (int dx = 0; dx < 7; dx++){
                        float wv = w2s[c*49 + dy*7 + dx];
                        #pragma unroll
                        for (int t = 0; t < 8; t++) acc2[t] = fmaf(wv, w16.a[t+dx], acc2[t]);
                    }
                }
            }
            int nw = 63 - xc; if (nw > 8) nw = 8;
            for (int t = 0; t < nw; t++) xs[(y0+1)*68 + 4 + xc + t] += acc2[t];
        }
        __syncthreads();
        // ---- residual of updated x -> rP (branchless stencil, b128 writes,
        // ---- row stride 68; tail zeroes rP col 63) ----
        if (act){
            float racc[8] = {};
            #pragma unroll
            for (int dy = 0; dy < 3; dy++){
                W16 w;
                const float4* rp = (const float4*)(xs + (y0 + dy)*68 + xc);
                w.v[0]=rp[0]; w.v[1]=rp[1]; w.v[2]=rp[2]; w.v[3]=rp[3];
                #pragma unroll
                for (int dx = 0; dx < 3; dx++){
                    float kv = ka[dy*3 + dx];
                    #pragma unroll
                    for (int t = 0; t < 8; t++) racc[t] = fmaf(kv, w.a[3 + t + dx], racc[t]);
                }
            }
            float out[8];
            #pragma unroll
            for (int t = 0; t < 8; t++){
                int ci = xc + t; if (ci > 62) ci = 62;
                float fv = fg[y0*ND + ci];
                out[t] = (xc + t < 63) ? (fv - racc[t]) : 0.f;
            }
            *(float4*)(rP + y0*68 + xc)     = make_float4(out[0],out[1],out[2],out[3]);
            *(float4*)(rP + y0*68 + xc + 4) = make_float4(out[4],out[5],out[6],out[7]);
        }
        __syncthreads();
        // ---- Phase A (Hermitian-paired; m=0 F=1) ----
        {
            float tr0,ti0=0.f,tr1,ti1=0.f,tr2,ti2=0.f,tr3,ti3=0.f;
            { F4 rv; rv.v = rP4[cg]; tr0=rv.a[0]; tr1=rv.a[1]; tr2=rv.a[2]; tr3=rv.a[3]; }
            #define A_PAIR(MM, JJ) { \
                F4 r1, r2; \
                r1.v = rP4[(MM)*17 + cg]; \
                r2.v = rP4[(63-(MM))*17 + cg]; \
                float fr = f4r.a[JJ], fi = f4i.a[JJ]; \
                float S0=r1.a[0]+r2.a[0], D0=r1.a[0]-r2.a[0]; \
                float S1=r1.a[1]+r2.a[1], D1=r1.a[1]-r2.a[1]; \
                float S2=r1.a[2]+r2.a[2], D2=r1.a[2]-r2.a[2]; \
                float S3=r1.a[3]+r2.a[3], D3=r1.a[3]-r2.a[3]; \
                tr0 = fmaf(fr, S0, tr0); ti0 = fmaf(fi, D0, ti0); \
                tr1 = fmaf(fr, S1, tr1); ti1 = fmaf(fi, D1, ti1); \
                tr2 = fmaf(fr, S2, tr2); ti2 = fmaf(fi, D2, ti2); \
                tr3 = fmaf(fr, S3, tr3); ti3 = fmaf(fi, D3, ti3); }
            {   // quad 0: m = 1..3
                F4 f4r, f4i; f4r.v = F4r[kt*17]; f4i.v = F4i[kt*17];
                A_PAIR(1, 1) A_PAIR(2, 2) A_PAIR(3, 3)
            }
            for (int mq = 1; mq < 8; mq++){   // m = 4..31
                F4 f4r, f4i;
                f4r.v = F4r[kt*17 + mq];
                f4i.v = F4i[kt*17 + mq];
                A_PAIR(4*mq + 0, 0) A_PAIR(4*mq + 1, 1)
                A_PAIR(4*mq + 2, 2) A_PAIR(4*mq + 3, 3)
            }
            #undef A_PAIR
            const int c0 = 4*cg;
            TtC[(c0+0)*32 + ((kt + c0 + 0) & 31)] = make_float2(tr0, ti0);
            TtC[(c0+1)*32 + ((kt + c0 + 1) & 31)] = make_float2(tr1, ti1);
            TtC[(c0+2)*32 + ((kt + c0 + 2) & 31)] = make_float2(tr2, ti2);
            TtC[(c0+3)*32 + ((kt + c0 + 3) & 31)] = make_float2(tr3, ti3);
        }
        // NO barrier: B reads TtC only from its own 16-thread kt-group (same wave)
        // ---- Phase B (Hermitian-paired; row 0 all-ones) ----
        {
            float R0r,R0i,R1r,R1i,R2r,R2i,R3r,R3i;
            {
                float2 T0 = TtC[kt & 31];          // n=0: F row = (1,0) — no F read
                R0r = T0.x; R0i = T0.y;
                R1r = T0.x; R1i = T0.y;
                R2r = T0.x; R2i = T0.y;
                R3r = T0.x; R3i = T0.y;
            }
            for (int np = 1; np <= 31; np++){
                int n2 = 63 - np;
                float2 T1 = TtC[np*32 + ((kt + np) & 31)];
                float2 T2 = TtC[n2*32 + ((kt + n2) & 31)];
                F4 fr, fi;
                fr.v = F4r[np*17 + cg];
                fi.v = F4i[np*17 + cg];
                float Sx = T1.x + T2.x, Dx = T1.x - T2.x;
                float Sy = T1.y + T2.y, Dy = T2.y - T1.y;
                R0r = fmaf(fr.a[0], Sx, R0r); R0r = fmaf(fi.a[0], Dy, R0r);
                R0i = fmaf(fi.a[0], Dx, R0i); R0i = fmaf(fr.a[0], Sy, R0i);
                R1r = fmaf(fr.a[1], Sx, R1r); R1r = fmaf(fi.a[1], Dy, R1r);
                R1i = fmaf(fi.a[1], Dx, R1i); R1i = fmaf(fr.a[1], Sy, R1i);
                R2r = fmaf(fr.a[2], Sx, R2r); R2r = fmaf(fi.a[2], Dy, R2r);
                R2i = fmaf(fi.a[2], Dx, R2i); R2i = fmaf(fr.a[2], Sy, R2i);
                R3r = fmaf(fr.a[3], Sx, R3r); R3r = fmaf(fi.a[3], Dy, R3r);
                R3i = fmaf(fi.a[3], Dx, R3i); R3i = fmaf(fr.a[3], Sy, R3i);
            }
            if (cg == 0){
                float2 dv = ((const float2*)dvs)[kt];
                ds_r[kt] = R0r*dv.x + R0i*dv.y;
                ds_i[kt] = R0r*dv.y - R0i*dv.x;
            }
            float4 vA = vc4s[kt*32 + 2*cg];
            float4 vB = vc4s[kt*32 + 2*cg + 1];
            const int c0 = 4*cg, rot = kt;
            MC2[kt*64 + ((c0+0 + rot) & 63)] = make_float2(R0r*vA.x - R0i*vA.y, R0r*vA.y + R0i*vA.x);
            MC2[kt*64 + ((c0+1 + rot) & 63)] = make_float2(R1r*vA.z - R1i*vA.w, R1r*vA.w + R1i*vA.z);
            MC2[kt*64 + ((c0+2 + rot) & 63)] = make_float2(R2r*vB.x - R2i*vB.y, R2r*vB.y + R2i*vB.x);
            MC2[kt*64 + ((c0+3 + rot) & 63)] = make_float2(R3r*vB.z - R3i*vB.w, R3r*vB.w + R3i*vB.z);
        }
        // NO barrier: D reads only MC2 row kt, written by its own kt-group
        // ---- Phase D (Hermitian-paired, same F-quad sharing) ----
        {
            const int rot = kt;
            float C0r,C0i,C1r,C1i,C2r,C2i,C3r,C3i;
            {
                float2 M0 = MC2[kt*64 + (rot & 63)];   // l=0: F row = (1,0)
                C0r = M0.x; C0i = M0.y;
                C1r = M0.x; C1i = M0.y;
                C2r = M0.x; C2i = M0.y;
                C3r = M0.x; C3i = M0.y;
            }
            for (int lp = 1; lp <= 31; lp++){
                int l2 = 63 - lp;
                float2 M1 = MC2[kt*64 + ((lp + rot) & 63)];
                float2 M2 = MC2[kt*64 + ((l2 + rot) & 63)];
                F4 fr, fi;
                fr.v = F4r[lp*17 + cg];
                fi.v = F4i[lp*17 + cg];
                float SMx = M1.x + M2.x, DMx = M2.x - M1.x;
                float SMy = M1.y + M2.y, DMy = M1.y - M2.y;
                C0r = fmaf(fr.a[0], SMx, C0r); C0r = fmaf(fi.a[0], DMy, C0r);
                C0i = fmaf(fr.a[0], SMy, C0i); C0i = fmaf(fi.a[0], DMx, C0i);
                C1r = fmaf(fr.a[1], SMx, C1r); C1r = fmaf(fi.a[1], DMy, C1r);
                C1i = fmaf(fr.a[1], SMy, C1i); C1i = fmaf(fi.a[1], DMx, C1i);
                C2r = fmaf(fr.a[2], SMx, C2r); C2r = fmaf(fi.a[2], DMy, C2r);
                C2i = fmaf(fr.a[2], SMy, C2i); C2i = fmaf(fi.a[2], DMx, C2i);
                C3r = fmaf(fr.a[3], SMx, C3r); C3r = fmaf(fi.a[3], DMy, C3r);
                C3i = fmaf(fr.a[3], SMy, C3i); C3i = fmaf(fi.a[3], DMx, C3i);
            }
            float sc2 = (kt == 0) ? 0.5f : 1.0f;
            CC4[kt*33 + 2*cg]     = make_float4(C0r*sc2, C0i*sc2, C1r*sc2, C1i*sc2);
            CC4[kt*33 + 2*cg + 1] = make_float4(C2r*sc2, C2i*sc2, C3r*sc2, C3i*sc2);
        }
        __syncthreads();
        // ---- Phase E: mirror-row pairing, F from LDS stride-17 quads ----
        if (tid < 256){
            const int pr = tid >> 3, qb = tid & 7;
            float sr[8] = {}, si[8] = {};
            float er = 0.f, ei = 0.f;
            for (int nq = 0; nq < 8; nq++){
                F4 f4r, f4i;
                f4r.v = F4r[pr*17 + nq];
                f4i.v = F4i[pr*17 + nq];
                #pragma unroll
                for (int j = 0; j < 4; j++){
                    int n = 4*nq + j;
                    float fr = f4r.a[j], fi = f4i.a[j];
                    float4 cA = CC4[n*33 + qb];
                    float4 cB = CC4[n*33 + qb + 8];
                    float4 cC = CC4[n*33 + qb + 16];
                    float4 cD = CC4[n*33 + qb + 24];
                    sr[0]=fmaf(fr,cA.x,sr[0]); si[0]=fmaf(fi,cA.y,si[0]);
                    sr[1]=fmaf(fr,cA.z,sr[1]); si[1]=fmaf(fi,cA.w,si[1]);
                    sr[2]=fmaf(fr,cB.x,sr[2]); si[2]=fmaf(fi,cB.y,si[2]);
                    sr[3]=fmaf(fr,cB.z,sr[3]); si[3]=fmaf(fi,cB.w,si[3]);
                    sr[4]=fmaf(fr,cC.x,sr[4]); si[4]=fmaf(fi,cC.y,si[4]);
                    sr[5]=fmaf(fr,cC.z,sr[5]); si[5]=fmaf(fi,cC.w,si[5]);
                    sr[6]=fmaf(fr,cD.x,sr[6]); si[6]=fmaf(fi,cD.y,si[6]);
                    sr[7]=fmaf(fr,cD.z,sr[7]); si[7]=fmaf(fi,cD.w,si[7]);
                    er = fmaf(fr, ds_r[n], er); ei = fmaf(fi, ds_i[n], ei);
                }
            }
            {   // row pr: y = sr+si, e = er-ei  (padded xs base: +68, +4)
                float e0 = er - ei;
                float* xrow = xs + (pr+1)*68 + 4;
                float2* xp0 = (float2*)(xrow + 2*qb);
                float2* xp1 = (float2*)(xrow + 2*qb + 16);
                float2* xp2 = (float2*)(xrow + 2*qb + 32);
                float2* xp3 = (float2*)(xrow + 2*qb + 48);
                float2 v0=*xp0, v1=*xp1, v2=*xp2, v3=*xp3;
                v0.x += 2.f*(sr[0]+si[0]) + e0; v0.y += 2.f*(sr[1]+si[1]) + e0;
                v1.x += 2.f*(sr[2]+si[2]) + e0; v1.y += 2.f*(sr[3]+si[3]) + e0;
                v2.x += 2.f*(sr[4]+si[4]) + e0; v2.y += 2.f*(sr[5]+si[5]) + e0;
                v3.x += 2.f*(sr[6]+si[6]) + e0; v3.y += 2.f*(sr[7]+si[7]) + e0;
                *xp0=v0; *xp1=v1; *xp2=v2; *xp3=v3;
            }
            if (pr > 0){ // row 63-pr: fi -> -fi  =>  y = sr-si, e = er+ei
                float e1 = er + ei;
                float* xrow = xs + (63-pr+1)*68 + 4;
                float2* xp0 = (float2*)(xrow + 2*qb);
                float2* xp1 = (float2*)(xrow + 2*qb + 16);
                float2* xp2 = (float2*)(xrow + 2*qb + 32);
                float2* xp3 = (float2*)(xrow + 2*qb + 48);
                float2 v0=*xp0, v1=*xp1, v2=*xp2, v3=*xp3;
                v0.x += 2.f*(sr[0]-si[0]) + e1; v0.y += 2.f*(sr[1]-si[1]) + e1;
                v1.x += 2.f*(sr[2]-si[2]) + e1; v1.y += 2.f*(sr[3]-si[3]) + e1;
                v2.x += 2.f*(sr[4]-si[4]) + e1; v2.y += 2.f*(sr[5]-si[5]) + e1;
                v3.x += 2.f*(sr[6]-si[6]) + e1; v3.y += 2.f*(sr[7]-si[7]) + e1;
                *xp0=v0; *xp1=v1; *xp2=v2; *xp3=v3;
            }
        }
        __syncthreads();
    }
    // ---- final residual + norm (branchless stencil on padded xs) ----
    float s = 0.f;
    if (act){
        float racc[8] = {};
        #pragma unroll
        for (int dy = 0; dy < 3; dy++){
            W16 w;
            const float4* rp = (const float4*)(xs + (y0 + dy)*68 + xc);
            w.v[0]=rp[0]; w.v[1]=rp[1]; w.v[2]=rp[2]; w.v[3]=rp[3];
            #pragma unroll
            for (int dx = 0; dx < 3; dx++){
                float kv = ka[dy*3 + dx];
                #pragma unroll
                for (int t = 0; t < 8; t++) racc[t] = fmaf(kv, w.a[3 + t + dx], racc[t]);
            }
        }
        #pragma unroll
        for (int t = 0; t < 8; t++){
            if (xc + t < 63){
                float r = fg[y0*ND + xc + t] - racc[t];
                s = fmaf(r, r, s);
            }
        }
    }
    #pragma unroll
    for (int off = 32; off > 0; off >>= 1) s += __shfl_down(s, off, 64);
    int lane = tid & 63, w = tid >> 6;
    if (lane == 0) red[w] = s;
    __syncthreads();
    if (tid == 0){
        float t = 0.f;
        #pragma unroll
        for (int i = 0; i < 8; i++) t += red[i];
        atomicAdd(accg, t);
    }
}

__global__ void k_final(const float* __restrict__ acc, float* __restrict__ out){
    if (threadIdx.x == 0 && blockIdx.x == 0) out[0] = sqrtf(acc[0]) * (1.0f/256.0f);
}

// ---------------- host ------------------------------------------------------
extern "C" void kernel_launch(void* const* d_in, const int* in_sizes, int n_in,
                              void* d_out, int out_size, void* d_ws, size_t ws_size,
                              hipStream_t stream){
    const float* x0     = (const float*)d_in[0];
    const float* f      = (const float*)d_in[1];
    const float* kA     = (const float*)d_in[2];
    const float* fc1_w1 = (const float*)d_in[3];
    const float* fc1_b1 = (const float*)d_in[4];
    const float* fc1_w2 = (const float*)d_in[5];
    const float* fc1_b2 = (const float*)d_in[6];
    const float* fc2_w1 = (const float*)d_in[7];
    const float* fc2_b1 = (const float*)d_in[8];
    const float* fc2_w2 = (const float*)d_in[9];
    const float* fc2_b2 = (const float*)d_in[10];
    const float* ct1_w  = (const float*)d_in[11];
    const float* ct1_b  = (const float*)d_in[12];
    const float* ct2_w  = (const float*)d_in[13];
    const float* ct2_b  = (const float*)d_in[14];
    const float* ct3_w  = (const float*)d_in[15];
    const float* ct3_b  = (const float*)d_in[16];
    const float* ct4_w  = (const float*)d_in[17];
    const float* ct4_b  = (const float*)d_in[18];
    const float* ct5_w  = (const float*)d_in[19];
    const float* ct5_b  = (const float*)d_in[20];
    float* out = (float*)d_out;

    float* ws = (float*)d_ws;
    size_t off = 0;
    auto take = [&](size_t n){ float* p = ws + off; off += (n + 63) & ~(size_t)63; return p; };
    float* acc = take(64);
    float* c4  = take((size_t)NB*32*1089);
    float* c3  = take((size_t)NB*9248);
    (void)ws_size; (void)in_sizes; (void)n_in; (void)out_size;

    k_ct123<<<NB, 1024, 0, stream>>>(kA, ct1_w, ct2_w, ct3_w,
                                     ct1_b, ct2_b, ct3_b, c3, acc);
    k_ct4<<<NB*2, 512, 0, stream>>>(c3, ct4_w, ct4_b, c4);
    k_solve<<<NB, 512, 0, stream>>>(x0, f, kA,
                                    fc1_w1, fc1_b1, fc1_w2, fc1_b2,
                                    fc2_w1, fc2_b1, fc2_w2, fc2_b2,
                                    ct5_w, ct5_b, c4, acc);
    k_final<<<1, 64, 0, stream>>>(acc, out);
}

// Round 17
// 323.833 us; speedup vs baseline: 1.0322x; 1.0322x over previous
//
#include <hip/hip_runtime.h>
#include <math.h>

#define NB   256
#define ND   63
#define NN   3969        // 63*63
#define WST  1028        // wbuf tap stride (1028%32=4 -> bank spread across taps)

__device__ __forceinline__ float gelu_f(float v){
    return 0.5f * v * (1.0f + erff(v * 0.70710678118654752440f));
}

#define FMA4(A, W, S) { (A).x=fmaf((W).x,(S),(A).x); (A).y=fmaf((W).y,(S),(A).y); \
                        (A).z=fmaf((W).z,(S),(A).z); (A).w=fmaf((W).w,(S),(A).w); }

union F4  { float4 v;    float a[4];  };
union W16 { float4 v[4]; float a[16]; };

__device__ __forceinline__ float4 gelu4(const F4& x){
    float4 r;
    r.x = gelu_f(x.a[0]); r.y = gelu_f(x.a[1]);
    r.z = gelu_f(x.a[2]); r.w = gelu_f(x.a[3]);
    return r;
}

// pair-base decode: units 0..H-1 are x-pairs (ox,ox+2), unit H is the singleton 2H.
__device__ __forceinline__ int dec_base(int uc, int H){
    int h2 = H >> 1;
    return (uc < h2) ? 4*uc : (uc < H) ? 4*(uc - h2) + 1 : 2*H;
}

// ---- 2x2-quad ConvTranspose stage (NT = block size) ----
template<int SIN, int SOUT, int OST, int NT>
__device__ __forceinline__ void ct_quad_stage(const float* __restrict__ cin,
                                              float* __restrict__ cout,
                                              const float* __restrict__ wb,
                                              const float* __restrict__ bsv,
                                              int tid){
    const int H  = (SOUT - 1) >> 1;
    const int UX = H + 1;
    const int NU = UX * UX * 8;
    for (int u = tid; u < NU; u += NT){
        const int cell = u >> 3, q = u & 7;
        const int ucy = cell / UX, ucx = cell - ucy*UX;
        const int oy = dec_base(ucy, H), ox = dec_base(ucx, H);
        const bool vx = (ox + 2 <= 2*H), vy = (oy + 2 <= 2*H);
        int nky, kyA[2], iyA[2];
        if (oy & 1){ nky=2; kyA[0]=0; iyA[0]=(oy+1)>>1; kyA[1]=2; iyA[1]=(oy-1)>>1; }
        else       { nky=1; kyA[0]=1; iyA[0]=oy>>1; kyA[1]=1; iyA[1]=0; }
        int nkx, kxA[2], ixA[2];
        if (ox & 1){ nkx=2; kxA[0]=0; ixA[0]=(ox+1)>>1; kxA[1]=2; ixA[1]=(ox-1)>>1; }
        else       { nkx=1; kxA[0]=1; ixA[0]=ox>>1; kxA[1]=1; ixA[1]=0; }
        F4 a00, a01, a10, a11;
        a00.v = ((const float4*)bsv)[q]; a01.v = a00.v; a10.v = a00.v; a11.v = a00.v;
        for (int yi = 0; yi < nky; yi++)
        for (int xi = 0; xi < nkx; xi++){
            const float* wp  = wb + (kyA[yi]*3 + kxA[xi])*WST + 4*q;
            const float* p00 = cin + (iyA[yi]*SIN + ixA[xi])*36;
            const float* p01 = p00 + 36;
            const float* p10 = p00 + SIN*36;
            const float* p11 = p10 + 36;
            #pragma unroll
            for (int g = 0; g < 8; g++){
                F4 i00, i01, i10, i11;
                i00.v = *(const float4*)(p00 + 4*g);
                i01.v = *(const float4*)(p01 + 4*g);
                i10.v = *(const float4*)(p10 + 4*g);
                i11.v = *(const float4*)(p11 + 4*g);
                #pragma unroll
                for (int cc = 0; cc < 4; cc++){
                    float4 w = *(const float4*)(wp + (4*g + cc)*32);
                    FMA4(a00.v, w, i00.a[cc]);
                    FMA4(a01.v, w, i01.a[cc]);
                    FMA4(a10.v, w, i10.a[cc]);
                    FMA4(a11.v, w, i11.a[cc]);
                }
            }
        }
        float4 g00 = gelu4(a00), g01 = gelu4(a01), g10 = gelu4(a10), g11 = gelu4(a11);
        size_t base = (size_t)(oy*SOUT + ox)*OST + 4*q;
        *(float4*)(cout + base) = g00;
        if (vx)        *(float4*)(cout + base + 2*(size_t)OST) = g01;
        if (vy)        *(float4*)(cout + base + 2*(size_t)SOUT*OST) = g10;
        if (vx && vy)  *(float4*)(cout + base + 2*(size_t)(SOUT+1)*OST) = g11;
    }
}

// ---- fused ct1..ct4 per sample (1024 threads; r14 best-verified config) ----
__global__ __launch_bounds__(1024)
__attribute__((amdgpu_waves_per_eu(4, 4)))
void k_ct1234(const float* __restrict__ kA,
              const float* __restrict__ cw1,
              const float* __restrict__ cw2,
              const float* __restrict__ cw3,
              const float* __restrict__ cw4,
              const float* __restrict__ b1,
              const float* __restrict__ b2,
              const float* __restrict__ b3,
              const float* __restrict__ b4,
              float* __restrict__ c4out,
              float* __restrict__ acc){
    __shared__ __align__(16) float wbuf[9*WST];  // [tap(1028)][ci][co32]
    __shared__ __align__(16) float w1s[9*36];    // [tap(36)][co32]
    __shared__ __align__(16) float c1s[31*36];   // [px][ci] stride 36
    __shared__ __align__(16) float c2s[91*36];
    __shared__ __align__(16) float c3s[307*36];
    __shared__ float b1s[32], b2s[32], b3s[32], b4s[32];
    const int b = blockIdx.x, tid = threadIdx.x;
    if (b == 0 && tid == 0) acc[0] = 0.f;
    for (int i = tid; i < 9216; i += 1024){
        int ci = i / 288, co = (i / 9) & 31, tap = i % 9;
        wbuf[tap*WST + ci*32 + co] = cw2[i];
    }
    if (tid < 288) w1s[(tid % 9)*36 + tid/9] = cw1[tid];
    if (tid < 32){ b1s[tid]=b1[tid]; b2s[tid]=b2[tid]; b3s[tid]=b3[tid]; b4s[tid]=b4[tid]; }
    __syncthreads();
    // ---- ct1: 3x3 -> 5x5, 1->32. 200 units ----
    if (tid < 200){
        int px = tid >> 3, q = tid & 7;
        int oy = px / 5, ox = px % 5;
        F4 a4; a4.v = ((const float4*)b1s)[q];
        int nky, kyA[2], iyA[2];
        if (oy & 1){ nky=2; kyA[0]=0; iyA[0]=(oy+1)/2; kyA[1]=2; iyA[1]=(oy-1)/2; }
        else       { nky=1; kyA[0]=1; iyA[0]=oy/2; kyA[1]=1; iyA[1]=0; }
        int nkx, kxA[2], ixA[2];
        if (ox & 1){ nkx=2; kxA[0]=0; ixA[0]=(ox+1)/2; kxA[1]=2; ixA[1]=(ox-1)/2; }
        else       { nkx=1; kxA[0]=1; ixA[0]=ox/2; kxA[1]=1; ixA[1]=0; }
        const float* ab = kA + b*9;
        for (int yi = 0; yi < nky; yi++)
        for (int xi = 0; xi < nkx; xi++){
            float v = ab[iyA[yi]*3 + ixA[xi]];
            float4 w = *(const float4*)(w1s + (kyA[yi]*3 + kxA[xi])*36 + 4*q);
            FMA4(a4.v, w, v);
        }
        *(float4*)(c1s + px*36 + 4*q) = gelu4(a4);
    }
    __syncthreads();
    ct_quad_stage<5, 9, 36, 1024>(c1s, c2s, wbuf, b2s, tid);   // ct2: 5->9
    __syncthreads();
    for (int i = tid; i < 9216; i += 1024){
        int ci = i / 288, co = (i / 9) & 31, tap = i % 9;
        wbuf[tap*WST + ci*32 + co] = cw3[i];
    }
    __syncthreads();
    ct_quad_stage<9, 17, 36, 1024>(c2s, c3s, wbuf, b3s, tid);  // ct3: 9->17
    __syncthreads();
    for (int i = tid; i < 9216; i += 1024){
        int ci = i / 288, co = (i / 9) & 31, tap = i % 9;
        wbuf[tap*WST + ci*32 + co] = cw4[i];
    }
    __syncthreads();
    // ct4: 17->33, channel-last to global
    ct_quad_stage<17, 33, 32, 1024>(c3s, c4out + (size_t)b*(1089*32), wbuf, b4s, tid);
}

// ---------------- mega solver, 512 threads, Hermitian-halved DFT -------------
// Final state: 6 barriers/iter (data-flow minimum), Hermitian-halved A/B/D,
// mirror-paired E, branchless padded-xs stencils, bank-spread LDS layouts.
__global__ __launch_bounds__(512) void k_solve(const float* __restrict__ x0g,
                                               const float* __restrict__ f,
                                               const float* __restrict__ kAg,
                                               const float* __restrict__ w1a, const float* __restrict__ b1a,
                                               const float* __restrict__ w2a, const float* __restrict__ b2a,
                                               const float* __restrict__ w1b, const float* __restrict__ b1b,
                                               const float* __restrict__ w2b, const float* __restrict__ b2b,
                                               const float* __restrict__ cw5,
                                               const float* __restrict__ b5,
                                               const float* __restrict__ c4g,
                                               float* __restrict__ accg){
    __shared__ __align__(16) float xs[65*68 + 8];    // padded: 65 rows x stride 68
    __shared__ __align__(16) float U[17152 + 8];     // c5s / rs+tc0+tc1+tc2 / rP|TtC|MC|CC
    __shared__ __align__(16) float Fs_r[32*68 + 8];  // F real, rows 0..31, stride 68
    __shared__ __align__(16) float Fs_i[32*68 + 8];  // F imag
    __shared__ __align__(16) float vcs[4096];        // v rows 0..31 interleaved (f4)
    __shared__ float ws5b[9*68];
    __shared__ float w1s[148], w2s[148], dvs[64], ds_r[32], ds_i[32], red[8], hs[100];
    const int b = blockIdx.x, tid = threadIdx.x;
    float* rs  = U;
    float* tc0 = U + 4288;
    float* tc1 = U + 8576;
    float* tc2 = U + 12864;
    float*  rP  = U;                                 // 63 rows x stride 68
    const float4* rP4 = (const float4*)U;            // row stride 17 f4
    float2* TtC = (float2*)(U + 4352);               // 4352..8447
    float2* MC2 = (float2*)(U + 8448);               // 8448..12543 (disjoint from rP/TtC)
    float4* CC4 = (float4*)(U + 12544);              // 12544..16767
    float* c5s = U;
    const float4* F4r = (const float4*)Fs_r;
    const float4* F4i = (const float4*)Fs_i;
    const float4* vc4s = (const float4*)vcs;
    const float* fg = f + (size_t)b*NN;
    float ka[9];
    #pragma unroll
    for (int i = 0; i < 9; i++) ka[i] = kAg[b*9 + i];

    // ================= prologue =================
    for (int i = tid; i < 2176; i += 512){
        int r = i / 68, c = i % 68;
        float vr = 0.f, vi = 0.f;
        if (c < 63){
            int m = (r * c) % 63;
            float ang = 6.283185307179586f * (float)m / 63.0f;
            vr = cosf(ang); vi = -sinf(ang);
        }
        Fs_r[i] = vr; Fs_i[i] = vi;
    }
    // padded-xs boundary init (skip interior: rows 1..63 x cols 4..66)
    for (int i = tid; i < 4428; i += 512){
        int r = i / 68, c = i - r*68;
        bool interior = (r >= 1 && r <= 63 && c >= 4 && c <= 66);
        if (!interior) xs[i] = (r == 64 || c == 67) ? 1.f : 0.f;
    }
    for (int i = tid; i < 576; i += 512){
        int ci = i / 18, co = (i / 9) & 1, tap = i % 9;
        ws5b[tap*68 + ci*2 + co] = cw5[i];
    }
    for (int i = tid; i < NN; i += 512) xs[(i/ND + 1)*68 + (i%ND) + 4] = x0g[(size_t)b*NN + i];
    // hypernet MLP (both stacks), outputs straight into w1s/w2s
    if (tid < 100){
        float s = b1a[tid];
        #pragma unroll
        for (int i = 0; i < 9; i++) s = fmaf(ka[i], w1a[i*100 + tid], s);
        hs[tid] = gelu_f(s);
    }
    __syncthreads();
    if (tid < 147){
        float s = b2a[tid];
        for (int k = 0; k < 100; k++) s = fmaf(hs[k], w2a[k*147 + tid], s);
        w1s[tid] = s;
    }
    __syncthreads();
    if (tid < 100){
        float s = b1b[tid];
        #pragma unroll
        for (int i = 0; i < 9; i++) s = fmaf(ka[i], w1b[i*100 + tid], s);
        hs[tid] = gelu_f(s);
    }
    __syncthreads();
    if (tid < 147){
        float s = b2b[tid];
        for (int k = 0; k < 100; k++) s = fmaf(hs[k], w2b[k*147 + tid], s);
        w2s[tid] = s;
    }
    // ct5 from c4 -> c5s (in U)
    {
        const float* ib = c4g + (size_t)b * (1089*32);
        float bb0 = b5[0], bb1 = b5[1];
        for (int p = tid; p < NN; p += 512){
            int oy = p / ND, ox = p % ND;
            float a0 = bb0, a1 = bb1;
            int nky, kyA[2], iyA[2];
            if ((oy & 1) == 0){ nky=2; kyA[0]=0; iyA[0]=oy/2+1; kyA[1]=2; iyA[1]=oy/2; }
            else              { nky=1; kyA[0]=1; iyA[0]=(oy+1)/2; kyA[1]=1; iyA[1]=0; }
            int nkx, kxA[2], ixA[2];
            if ((ox & 1) == 0){ nkx=2; kxA[0]=0; ixA[0]=ox/2+1; kxA[1]=2; ixA[1]=ox/2; }
            else              { nkx=1; kxA[0]=1; ixA[0]=(ox+1)/2; kxA[1]=1; ixA[1]=0; }
            for (int yi = 0; yi < nky; yi++)
            for (int xi = 0; xi < nkx; xi++){
                const float* ip = ib + ((size_t)iyA[yi]*33 + ixA[xi])*32;
                const float* wp = ws5b + (kyA[yi]*3 + kxA[xi])*68;
                #pragma unroll
                for (int g = 0; g < 8; g++){
                    F4 iv; iv.v = *(const float4*)(ip + 4*g);
                    #pragma unroll
                    for (int q = 0; q < 4; q++){
                        int ci = 4*g + q;
                        a0 = fmaf(iv.a[q], wp[ci*2],   a0);
                        a1 = fmaf(iv.a[q], wp[ci*2+1], a1);
                    }
                }
            }
            c5s[p]      = a0;
            c5s[NN + p] = a1;
        }
    }
    __syncthreads();
    // build vcs (rows 0..31, interleaved re/im pairs) + dvs
    {
        const float sc = 1.0f / 3969.0f;
        float4* vout = (float4*)vcs;
        for (int i = tid; i < 1024; i += 512){
            int ky = i >> 5, ct2 = i & 31;
            float4 o;
            #pragma unroll
            for (int j = 0; j < 2; j++){
                int kx = 2*ct2 + j;
                float re = 0.f, im = 0.f;
                if (kx <= 31){ int o2 = 2*(ky*ND + kx); re = c5s[o2]*sc; im = c5s[o2+1]*sc; }
                else if (kx <= 62){
                    int sy = (ND - ky) % ND, sx = ND - kx;
                    int o2 = 2*(sy*ND + sx); re = c5s[o2]*sc; im = -c5s[o2+1]*sc;
                }
                if (j == 0){ o.x = re; o.y = im; } else { o.z = re; o.w = im; }
            }
            vout[i] = o;
        }
        if (tid < 32){
            float2 d = {0.f, 0.f};
            if (tid >= 1){
                int iA = (ND - tid) * ND, iB = tid * ND;
                d.x = (c5s[2*iA]     - c5s[2*iB])     * sc;
                d.y = (c5s[2*iA + 1] + c5s[2*iB + 1]) * sc;
            }
            ((float2*)dvs)[tid] = d;
        }
    }
    __syncthreads();

    const int kt = tid >> 4, cg = tid & 15;
    const bool act = tid < 504;
    const int y0 = tid >> 3, xc = 8*(tid & 7);

    for (int it = 0; it < 5; it++){
        // ---- residual -> rs: branchless stencil on padded xs ----
        if (act){
            float racc[8] = {};
            #pragma unroll
            for (int dy = 0; dy < 3; dy++){
                W16 w;
                const float4* rp = (const float4*)(xs + (y0 + dy)*68 + xc);
                w.v[0]=rp[0]; w.v[1]=rp[1]; w.v[2]=rp[2]; w.v[3]=rp[3];
                #pragma unroll
                for (int dx = 0; dx < 3; dx++){
                    float kv = ka[dy*3 + dx];
                    #pragma unroll
                    for (int t = 0; t < 8; t++) racc[t] = fmaf(kv, w.a[3 + t + dx], racc[t]);
                }
            }
            int nw = 63 - xc; if (nw > 8) nw = 8;
            const float* fr_ = fg + y0*ND + xc;
            for (int t = 0; t < nw; t++) rs[y0*68 + 3 + xc + t] = fr_[t] - racc[t];
        }
        // borders: cols {0,1,2,66,67} of 63 rows + 4-float tail, for each of
        // rs,tc0,tc1,tc2 (these bytes are scribbled by the DFT unions each iter)
        for (int i = tid; i < 1276; i += 512){
            int buf = i / 319, j = i - buf*319;
            float* base = U + buf*4288;
            int idx;
            if (j < 315){ int rr = j/5, cc = j - rr*5; idx = rr*68 + ((cc < 3) ? cc : 63 + cc); }
            else idx = 4284 + (j - 315);
            base[idx] = 0.f;
        }
        __syncthreads();
        // ---- smoother pass1: all 3 channels, shared row loads -> tc0/1/2 ----
        if (act){
            float A0[8] = {}, A1[8] = {}, A2[8] = {};
            for (int dy = 0; dy < 7; dy++){
                int ry = y0 + dy - 3;
                if (ry < 0 || ry >= 63) continue;
                W16 w16;
                const float4* rp = (const float4*)(rs + ry*68 + xc);
                w16.v[0]=rp[0]; w16.v[1]=rp[1]; w16.v[2]=rp[2]; w16.v[3]=rp[3];
                #pragma unroll
                for (int dx = 0; dx < 7; dx++){
                    float w0 = w1s[dy*7 + dx];
                    float w1 = w1s[49 + dy*7 + dx];
                    float w2 = w1s[98 + dy*7 + dx];
                    #pragma unroll
                    for (int t = 0; t < 8; t++){
                        float v = w16.a[t+dx];
                        A0[t] = fmaf(w0, v, A0[t]);
                        A1[t] = fmaf(w1, v, A1[t]);
                        A2[t] = fmaf(w2, v, A2[t]);
                    }
                }
            }
            int nw = 63 - xc; if (nw > 8) nw = 8;
            for (int t = 0; t < nw; t++){
                int o = y0*68 + 3 + xc + t;
                tc0[o] = A0[t]; tc1[o] = A1[t]; tc2[o] = A2[t];
            }
        }
        __syncthreads();
        // ---- smoother pass2: accumulate 3 channels, update x (padded layout) ----
        if (act){
            float acc2[8] = {};
            #pragma unroll
            for (int c = 0; c < 3; c++){
                const float* tcc = (c == 0) ? tc0 : (c == 1) ? tc1 : tc2;
                for (int dy = 0; dy < 7; dy++){
                    int ry = y0 + dy - 3;
                    if (ry < 0 || ry >= 63) continue;
                    W16 w16;
                    const float4* tp = (const float4*)(tcc + ry*68 + xc);
                    w16.v[0]=tp[0]; w16.v[1]=tp[1]; w16.v[2]=tp[2]; w16.v[3]=tp[3];
                    #pragma unroll
                    for (int dx = 0; dx < 7; dx++){
                        float wv = w2s[c*49 + dy*7 + dx];
                        #pragma unroll
                        for (int t = 0; t < 8; t++) acc2[t] = fmaf(wv, w16.a[t+dx], acc2[t]);
                    }
                }
            }
            int nw = 63 - xc; if (nw > 8) nw = 8;
            for (int t = 0; t < nw; t++) xs[(y0+1)*68 + 4 + xc + t] += acc2[t];
        }
        __syncthreads();
        // ---- residual of updated x -> rP (branchless stencil, b128 writes,
        // ---- row stride 68; tail zeroes rP col 63) ----
        if (act){
            float racc[8] = {};
            #pragma unroll
            for (int dy = 0; dy < 3; dy++){
                W16 w;
                const float4* rp = (const float4*)(xs + (y0 + dy)*68 + xc);
                w.v[0]=rp[0]; w.v[1]=rp[1]; w.v[2]=rp[2]; w.v[3]=rp[3];
                #pragma unroll
                for (int dx = 0; dx < 3; dx++){
                    float kv = ka[dy*3 + dx];
                    #pragma unroll
                    for (int t = 0; t < 8; t++) racc[t] = fmaf(kv, w.a[3 + t + dx], racc[t]);
                }
            }
            float out[8];
            #pragma unroll
            for (int t = 0; t < 8; t++){
                int ci = xc + t; if (ci > 62) ci = 62;
                float fv = fg[y0*ND + ci];
                out[t] = (xc + t < 63) ? (fv - racc[t]) : 0.f;
            }
            *(float4*)(rP + y0*68 + xc)     = make_float4(out[0],out[1],out[2],out[3]);
            *(float4*)(rP + y0*68 + xc + 4) = make_float4(out[4],out[5],out[6],out[7]);
        }
        __syncthreads();
        // ---- Phase A (Hermitian-paired; m=0 F=1) ----
        {
            float tr0,ti0=0.f,tr1,ti1=0.f,tr2,ti2=0.f,tr3,ti3=0.f;
            { F4 rv; rv.v = rP4[cg]; tr0=rv.a[0]; tr1=rv.a[1]; tr2=rv.a[2]; tr3=rv.a[3]; }
            #define A_PAIR(MM, JJ) { \
                F4 r1, r2; \
                r1.v = rP4[(MM)*17 + cg]; \
                r2.v = rP4[(63-(MM))*17 + cg]; \
                float fr = f4r.a[JJ], fi = f4i.a[JJ]; \
                float S0=r1.a[0]+r2.a[0], D0=r1.a[0]-r2.a[0]; \
                float S1=r1.a[1]+r2.a[1], D1=r1.a[1]-r2.a[1]; \
                float S2=r1.a[2]+r2.a[2], D2=r1.a[2]-r2.a[2]; \
                float S3=r1.a[3]+r2.a[3], D3=r1.a[3]-r2.a[3]; \
                tr0 = fmaf(fr, S0, tr0); ti0 = fmaf(fi, D0, ti0); \
                tr1 = fmaf(fr, S1, tr1); ti1 = fmaf(fi, D1, ti1); \
                tr2 = fmaf(fr, S2, tr2); ti2 = fmaf(fi, D2, ti2); \
                tr3 = fmaf(fr, S3, tr3); ti3 = fmaf(fi, D3, ti3); }
            {   // quad 0: m = 1..3
                F4 f4r, f4i; f4r.v = F4r[kt*17]; f4i.v = F4i[kt*17];
                A_PAIR(1, 1) A_PAIR(2, 2) A_PAIR(3, 3)
            }
            for (int mq = 1; mq < 8; mq++){   // m = 4..31
                F4 f4r, f4i;
                f4r.v = F4r[kt*17 + mq];
                f4i.v = F4i[kt*17 + mq];
                A_PAIR(4*mq + 0, 0) A_PAIR(4*mq + 1, 1)
                A_PAIR(4*mq + 2, 2) A_PAIR(4*mq + 3, 3)
            }
            #undef A_PAIR
            const int c0 = 4*cg;
            TtC[(c0+0)*32 + ((kt + c0 + 0) & 31)] = make_float2(tr0, ti0);
            TtC[(c0+1)*32 + ((kt + c0 + 1) & 31)] = make_float2(tr1, ti1);
            TtC[(c0+2)*32 + ((kt + c0 + 2) & 31)] = make_float2(tr2, ti2);
            TtC[(c0+3)*32 + ((kt + c0 + 3) & 31)] = make_float2(tr3, ti3);
        }
        // NO barrier: B reads TtC only from its own 16-thread kt-group (same wave)
        // ---- Phase B (Hermitian-paired; row 0 all-ones) ----
        {
            float R0r,R0i,R1r,R1i,R2r,R2i,R3r,R3i;
            {
                float2 T0 = TtC[kt & 31];          // n=0: F row = (1,0) — no F read
                R0r = T0.x; R0i = T0.y;
                R1r = T0.x; R1i = T0.y;
                R2r = T0.x; R2i = T0.y;
                R3r = T0.x; R3i = T0.y;
            }
            for (int np = 1; np <= 31; np++){
                int n2 = 63 - np;
                float2 T1 = TtC[np*32 + ((kt + np) & 31)];
                float2 T2 = TtC[n2*32 + ((kt + n2) & 31)];
                F4 fr, fi;
                fr.v = F4r[np*17 + cg];
                fi.v = F4i[np*17 + cg];
                float Sx = T1.x + T2.x, Dx = T1.x - T2.x;
                float Sy = T1.y + T2.y, Dy = T2.y - T1.y;
                R0r = fmaf(fr.a[0], Sx, R0r); R0r = fmaf(fi.a[0], Dy, R0r);
                R0i = fmaf(fi.a[0], Dx, R0i); R0i = fmaf(fr.a[0], Sy, R0i);
                R1r = fmaf(fr.a[1], Sx, R1r); R1r = fmaf(fi.a[1], Dy, R1r);
                R1i = fmaf(fi.a[1], Dx, R1i); R1i = fmaf(fr.a[1], Sy, R1i);
                R2r = fmaf(fr.a[2], Sx, R2r); R2r = fmaf(fi.a[2], Dy, R2r);
                R2i = fmaf(fi.a[2], Dx, R2i); R2i = fmaf(fr.a[2], Sy, R2i);
                R3r = fmaf(fr.a[3], Sx, R3r); R3r = fmaf(fi.a[3], Dy, R3r);
                R3i = fmaf(fi.a[3], Dx, R3i); R3i = fmaf(fr.a[3], Sy, R3i);
            }
            if (cg == 0){
                float2 dv = ((const float2*)dvs)[kt];
                ds_r[kt] = R0r*dv.x + R0i*dv.y;
                ds_i[kt] = R0r*dv.y - R0i*dv.x;
            }
            float4 vA = vc4s[kt*32 + 2*cg];
            float4 vB = vc4s[kt*32 + 2*cg + 1];
            const int c0 = 4*cg, rot = kt;
            MC2[kt*64 + ((c0+0 + rot) & 63)] = make_float2(R0r*vA.x - R0i*vA.y, R0r*vA.y + R0i*vA.x);
            MC2[kt*64 + ((c0+1 + rot) & 63)] = make_float2(R1r*vA.z - R1i*vA.w, R1r*vA.w + R1i*vA.z);
            MC2[kt*64 + ((c0+2 + rot) & 63)] = make_float2(R2r*vB.x - R2i*vB.y, R2r*vB.y + R2i*vB.x);
            MC2[kt*64 + ((c0+3 + rot) & 63)] = make_float2(R3r*vB.z - R3i*vB.w, R3r*vB.w + R3i*vB.z);
        }
        // NO barrier: D reads only MC2 row kt, written by its own kt-group
        // ---- Phase D (Hermitian-paired, same F-quad sharing) ----
        {
            const int rot = kt;
            float C0r,C0i,C1r,C1i,C2r,C2i,C3r,C3i;
            {
                float2 M0 = MC2[kt*64 + (rot & 63)];   // l=0: F row = (1,0)
                C0r = M0.x; C0i = M0.y;
                C1r = M0.x; C1i = M0.y;
                C2r = M0.x; C2i = M0.y;
                C3r = M0.x; C3i = M0.y;
            }
            for (int lp = 1; lp <= 31; lp++){
                int l2 = 63 - lp;
                float2 M1 = MC2[kt*64 + ((lp + rot) & 63)];
                float2 M2 = MC2[kt*64 + ((l2 + rot) & 63)];
                F4 fr, fi;
                fr.v = F4r[lp*17 + cg];
                fi.v = F4i[lp*17 + cg];
                float SMx = M1.x + M2.x, DMx = M2.x - M1.x;
                float SMy = M1.y + M2.y, DMy = M1.y - M2.y;
                C0r = fmaf(fr.a[0], SMx, C0r); C0r = fmaf(fi.a[0], DMy, C0r);
                C0i = fmaf(fr.a[0], SMy, C0i); C0i = fmaf(fi.a[0], DMx, C0i);
                C1r = fmaf(fr.a[1], SMx, C1r); C1r = fmaf(fi.a[1], DMy, C1r);
                C1i = fmaf(fr.a[1], SMy, C1i); C1i = fmaf(fi.a[1], DMx, C1i);
                C2r = fmaf(fr.a[2], SMx, C2r); C2r = fmaf(fi.a[2], DMy, C2r);
                C2i = fmaf(fr.a[2], SMy, C2i); C2i = fmaf(fi.a[2], DMx, C2i);
                C3r = fmaf(fr.a[3], SMx, C3r); C3r = fmaf(fi.a[3], DMy, C3r);
                C3i = fmaf(fr.a[3], SMy, C3i); C3i = fmaf(fi.a[3], DMx, C3i);
            }
            float sc2 = (kt == 0) ? 0.5f : 1.0f;
            CC4[kt*33 + 2*cg]     = make_float4(C0r*sc2, C0i*sc2, C1r*sc2, C1i*sc2);
            CC4[kt*33 + 2*cg + 1] = make_float4(C2r*sc2, C2i*sc2, C3r*sc2, C3i*sc2);
        }
        __syncthreads();
        // ---- Phase E: mirror-row pairing, F from LDS stride-17 quads ----
        if (tid < 256){
            const int pr = tid >> 3, qb = tid & 7;
            float sr[8] = {}, si[8] = {};
            float er = 0.f, ei = 0.f;
            for (int nq = 0; nq < 8; nq++){
                F4 f4r, f4i;
                f4r.v = F4r[pr*17 + nq];
                f4i.v = F4i[pr*17 + nq];
                #pragma unroll
                for (int j = 0; j < 4; j++){
                    int n = 4*nq + j;
                    float fr = f4r.a[j], fi = f4i.a[j];
                    float4 cA = CC4[n*33 + qb];
                    float4 cB = CC4[n*33 + qb + 8];
                    float4 cC = CC4[n*33 + qb + 16];
                    float4 cD = CC4[n*33 + qb + 24];
                    sr[0]=fmaf(fr,cA.x,sr[0]); si[0]=fmaf(fi,cA.y,si[0]);
                    sr[1]=fmaf(fr,cA.z,sr[1]); si[1]=fmaf(fi,cA.w,si[1]);
                    sr[2]=fmaf(fr,cB.x,sr[2]); si[2]=fmaf(fi,cB.y,si[2]);
                    sr[3]=fmaf(fr,cB.z,sr[3]); si[3]=fmaf(fi,cB.w,si[3]);
                    sr[4]=fmaf(fr,cC.x,sr[4]); si[4]=fmaf(fi,cC.y,si[4]);
                    sr[5]=fmaf(fr,cC.z,sr[5]); si[5]=fmaf(fi,cC.w,si[5]);
                    sr[6]=fmaf(fr,cD.x,sr[6]); si[6]=fmaf(fi,cD.y,si[6]);
                    sr[7]=fmaf(fr,cD.z,sr[7]); si[7]=fmaf(fi,cD.w,si[7]);
                    er = fmaf(fr, ds_r[n], er); ei = fmaf(fi, ds_i[n], ei);
                }
            }
            {   // row pr: y = sr+si, e = er-ei  (padded xs base: +68, +4)
                float e0 = er - ei;
                float* xrow = xs + (pr+1)*68 + 4;
                float2* xp0 = (float2*)(xrow + 2*qb);
                float2* xp1 = (float2*)(xrow + 2*qb + 16);
                float2* xp2 = (float2*)(xrow + 2*qb + 32);
                float2* xp3 = (float2*)(xrow + 2*qb + 48);
                float2 v0=*xp0, v1=*xp1, v2=*xp2, v3=*xp3;
                v0.x += 2.f*(sr[0]+si[0]) + e0; v0.y += 2.f*(sr[1]+si[1]) + e0;
                v1.x += 2.f*(sr[2]+si[2]) + e0; v1.y += 2.f*(sr[3]+si[3]) + e0;
                v2.x += 2.f*(sr[4]+si[4]) + e0; v2.y += 2.f*(sr[5]+si[5]) + e0;
                v3.x += 2.f*(sr[6]+si[6]) + e0; v3.y += 2.f*(sr[7]+si[7]) + e0;
                *xp0=v0; *xp1=v1; *xp2=v2; *xp3=v3;
            }
            if (pr > 0){ // row 63-pr: fi -> -fi  =>  y = sr-si, e = er+ei
                float e1 = er + ei;
                float* xrow = xs + (63-pr+1)*68 + 4;
                float2* xp0 = (float2*)(xrow + 2*qb);
                float2* xp1 = (float2*)(xrow + 2*qb + 16);
                float2* xp2 = (float2*)(xrow + 2*qb + 32);
                float2* xp3 = (float2*)(xrow + 2*qb + 48);
                float2 v0=*xp0, v1=*xp1, v2=*xp2, v3=*xp3;
                v0.x += 2.f*(sr[0]-si[0]) + e1; v0.y += 2.f*(sr[1]-si[1]) + e1;
                v1.x += 2.f*(sr[2]-si[2]) + e1; v1.y += 2.f*(sr[3]-si[3]) + e1;
                v2.x += 2.f*(sr[4]-si[4]) + e1; v2.y += 2.f*(sr[5]-si[5]) + e1;
                v3.x += 2.f*(sr[6]-si[6]) + e1; v3.y += 2.f*(sr[7]-si[7]) + e1;
                *xp0=v0; *xp1=v1; *xp2=v2; *xp3=v3;
            }
        }
        __syncthreads();
    }
    // ---- final residual + norm (branchless stencil on padded xs) ----
    float s = 0.f;
    if (act){
        float racc[8] = {};
        #pragma unroll
        for (int dy = 0; dy < 3; dy++){
            W16 w;
            const float4* rp = (const float4*)(xs + (y0 + dy)*68 + xc);
            w.v[0]=rp[0]; w.v[1]=rp[1]; w.v[2]=rp[2]; w.v[3]=rp[3];
            #pragma unroll
            for (int dx = 0; dx < 3; dx++){
                float kv = ka[dy*3 + dx];
                #pragma unroll
                for (int t = 0; t < 8; t++) racc[t] = fmaf(kv, w.a[3 + t + dx], racc[t]);
            }
        }
        #pragma unroll
        for (int t = 0; t < 8; t++){
            if (xc + t < 63){
                float r = fg[y0*ND + xc + t] - racc[t];
                s = fmaf(r, r, s);
            }
        }
    }
    #pragma unroll
    for (int off = 32; off > 0; off >>= 1) s += __shfl_down(s, off, 64);
    int lane = tid & 63, w = tid >> 6;
    if (lane == 0) red[w] = s;
    __syncthreads();
    if (tid == 0){
        float t = 0.f;
        #pragma unroll
        for (int i = 0; i < 8; i++) t += red[i];
        atomicAdd(accg, t);
    }
}

__global__ void k_final(const float* __restrict__ acc, float* __restrict__ out){
    if (threadIdx.x == 0 && blockIdx.x == 0) out[0] = sqrtf(acc[0]) * (1.0f/256.0f);
}

// ---------------- host ------------------------------------------------------
extern "C" void kernel_launch(void* const* d_in, const int* in_sizes, int n_in,
                              void* d_out, int out_size, void* d_ws, size_t ws_size,
                              hipStream_t stream){
    const float* x0     = (const float*)d_in[0];
    const float* f      = (const float*)d_in[1];
    const float* kA     = (const float*)d_in[2];
    const float* fc1_w1 = (const float*)d_in[3];
    const float* fc1_b1 = (const float*)d_in[4];
    const float* fc1_w2 = (const float*)d_in[5];
    const float* fc1_b2 = (const float*)d_in[6];
    const float* fc2_w1 = (const float*)d_in[7];
    const float* fc2_b1 = (const float*)d_in[8];
    const float* fc2_w2 = (const float*)d_in[9];
    const float* fc2_b2 = (const float*)d_in[10];
    const float* ct1_w  = (const float*)d_in[11];
    const float* ct1_b  = (const float*)d_in[12];
    const float* ct2_w  = (const float*)d_in[13];
    const float* ct2_b  = (const float*)d_in[14];
    const float* ct3_w  = (const float*)d_in[15];
    const float* ct3_b  = (const float*)d_in[16];
    const float* ct4_w  = (const float*)d_in[17];
    const float* ct4_b  = (const float*)d_in[18];
    const float* ct5_w  = (const float*)d_in[19];
    const float* ct5_b  = (const float*)d_in[20];
    float* out = (float*)d_out;

    float* ws = (float*)d_ws;
    size_t off = 0;
    auto take = [&](size_t n){ float* p = ws + off; off += (n + 63) & ~(size_t)63; return p; };
    float* acc = take(64);
    float* c4  = take((size_t)NB*32*1089);
    (void)ws_size; (void)in_sizes; (void)n_in; (void)out_size;

    k_ct1234<<<NB, 1024, 0, stream>>>(kA, ct1_w, ct2_w, ct3_w, ct4_w,
                                      ct1_b, ct2_b, ct3_b, ct4_b, c4, acc);
    k_solve<<<NB, 512, 0, stream>>>(x0, f, kA,
                                    fc1_w1, fc1_b1, fc1_w2, fc1_b2,
                                    fc2_w1, fc2_b1, fc2_w2, fc2_b2,
                                    ct5_w, ct5_b, c4, acc);
    k_final<<<1, 64, 0, stream>>>(acc, out);
}